// Round 10
// baseline (115.797 us; speedup 1.0000x reference)
//
#include <hip/hip_runtime.h>
#include <hip/hip_bf16.h>

#define BATCH 8
#define CH    256
#define NN    1024
#define DD    32

// ws layout (bf16 shorts):
//   qT [b][i][d]   (scale*log2e folded)      512 KB
//   kT [b][j][d]   (rp + bias folded)        512 KB
//   v2 [b][jt32=32][ct=16][lane=64][sub=2][jj=4]  4 MB
//        element (c,j): jt=j>>5, ct=c>>4, lane=((j>>2)&3)*16+(c&15),
//                       sub=(j>>4)&1, jj=j&3   (16x16x16 A-frag-ready)
//   wf [mf=20][kc=8][lane=64][jj=8]          160 KB (W in x32 A-frag bf16)
#define QT_OFF 0
#define KT_OFF (BATCH * NN * DD)
#define V_OFF  (2 * BATCH * NN * DD)
#define V2_B   (NN * CH)                       // shorts per batch in v2
#define WF_OFF (V_OFF + BATCH * V2_B)          // 2621440

// 1/sqrt(32) * log2(e): softmax via exp2 (v_exp_f32 is native 2^x)
#define SCALE_Q (0.17677669529663687f * 1.4426950408889634f)
#define INV31 (1.0f / 31.0f)

typedef __attribute__((ext_vector_type(4))) float f32x4;
typedef __attribute__((ext_vector_type(8))) short bf16x8;
typedef __attribute__((ext_vector_type(4))) short bf16x4;

__device__ __forceinline__ unsigned int packbf2(float lo, float hi) {
    __hip_bfloat162 h = __float22bfloat162_rn(make_float2(lo, hi));
    union { __hip_bfloat162 h; unsigned int u; } cv; cv.h = h;
    return cv.u;
}
__device__ __forceinline__ unsigned short f2bf(float x) {
    union { float f; unsigned int u; } v; v.f = x;
    return (unsigned short)((v.u + 0x7FFFu + ((v.u >> 16) & 1u)) >> 16);
}

// ---------------------------------------------------------------------------
// Kernel W: repack W_all (320x256 fp32) into MFMA-A-fragment-ready bf16.
// ---------------------------------------------------------------------------
__global__ __launch_bounds__(256) void wrepack_kernel(
    const float* __restrict__ Wq, const float* __restrict__ Wk,
    const float* __restrict__ Wv, unsigned short* __restrict__ ws)
{
    const int gid = blockIdx.x * 256 + threadIdx.x;   // 0..20479
    const int e = gid * 4;
    const int m = e >> 8;
    const int k = e & 255;
    const float* src = (m < 32) ? (Wq + m * CH + k)
                     : (m < 64) ? (Wk + (m - 32) * CH + k)
                                : (Wv + (m - 64) * CH + k);
    const float4 w = *(const float4*)src;
    const int mf = m >> 4, kc = k >> 5;
    const int lf = ((k >> 3) & 3) * 16 + (m & 15);
    const int jj = k & 7;                              // 0 or 4
    uint2 st = { packbf2(w.x, w.y), packbf2(w.z, w.w) };
    *(uint2*)(ws + WF_OFF + ((size_t)(mf * 8 + kc) * 64 + lf) * 8 + jj) = st;
}

// ---------------------------------------------------------------------------
// Kernel P: MFMA projection, 2-deep pipelined across kc (HBM ~900 cyc vs
// ~100 cyc/stage issue: 2-deep x 8 waves/CU fully covers).
// ---------------------------------------------------------------------------
__global__ __launch_bounds__(256, 2) void proj_kernel(
    const float* __restrict__ x,
    const float* __restrict__ bq, const float* __restrict__ bk,
    const float* __restrict__ bv, const float* __restrict__ Wr,
    unsigned short* __restrict__ ws)
{
    const int nt   = blockIdx.x;   // 0..63
    const int b    = blockIdx.y;   // 0..7
    const int tid  = threadIdx.x;
    const int wv   = tid >> 6;     // 0..3 (m-group)
    const int lane = tid & 63;
    const int n16  = lane & 15;
    const int q4   = lane >> 4;
    const int n    = nt * 16 + n16;

    f32x4 acc[5];
#pragma unroll
    for (int t = 0; t < 5; t++) acc[t] = (f32x4){0.f, 0.f, 0.f, 0.f};

    const unsigned short* wfl = ws + WF_OFF + (size_t)lane * 8;
    const float* xb = x + (size_t)b * CH * NN + n;

    float  bx[3][8];
    bf16x8 af[3][5];
#pragma unroll
    for (int s = 0; s < 2; s++) {
        const int kofs = s * 32 + q4 * 8;
#pragma unroll
        for (int jj = 0; jj < 8; jj++)
            bx[s][jj] = xb[(size_t)(kofs + jj) * NN];
#pragma unroll
        for (int t = 0; t < 5; t++)
            af[s][t] = *(const bf16x8*)(wfl + (size_t)((wv * 5 + t) * 8 + s) * 512);
    }

#pragma unroll
    for (int kc = 0; kc < 8; kc++) {
        const int s = kc % 3;
        if (kc < 6) {
            const int sp = (kc + 2) % 3;
            const int kofs = (kc + 2) * 32 + q4 * 8;
#pragma unroll
            for (int jj = 0; jj < 8; jj++)
                bx[sp][jj] = xb[(size_t)(kofs + jj) * NN];
#pragma unroll
            for (int t = 0; t < 5; t++)
                af[sp][t] = *(const bf16x8*)(wfl + (size_t)((wv * 5 + t) * 8 + kc + 2) * 512);
        }
        union { unsigned int u[4]; bf16x8 v; } bf;
#pragma unroll
        for (int p = 0; p < 4; p++) bf.u[p] = packbf2(bx[s][2 * p], bx[s][2 * p + 1]);
#pragma unroll
        for (int t = 0; t < 5; t++)
            acc[t] = __builtin_amdgcn_mfma_f32_16x16x32_bf16(af[s][t], bf.v, acc[t], 0, 0, 0);
    }

    const int jj4 = n & 3;          // v2 sub-indices for this thread's j (= n)
    const int sub = (n >> 4) & 1;
    const int lq  = (n >> 2) & 3;
    const int jt  = n >> 5;
#pragma unroll
    for (int t = 0; t < 5; t++) {
        const int mf = wv * 5 + t;
        const int mb = mf * 16 + q4 * 4;
        if (mb < 32) {
            const float r0 = (acc[t][0] + bq[mb + 0]) * SCALE_Q;
            const float r1 = (acc[t][1] + bq[mb + 1]) * SCALE_Q;
            const float r2 = (acc[t][2] + bq[mb + 2]) * SCALE_Q;
            const float r3 = (acc[t][3] + bq[mb + 3]) * SCALE_Q;
            uint2 st = { packbf2(r0, r1), packbf2(r2, r3) };
            *(uint2*)(ws + QT_OFF + (size_t)(b * NN + n) * DD + mb) = st;
        } else if (mb < 64) {
            const int d = mb - 32;
            const float An = (float)(n >> 5) * INV31;
            const float Bn = (float)(n & 31) * INV31;
            float r[4];
#pragma unroll
            for (int rr = 0; rr < 4; rr++)
                r[rr] = acc[t][rr] + bk[d + rr] - An * Wr[2 * (d + rr)] - Bn * Wr[2 * (d + rr) + 1];
            uint2 st = { packbf2(r[0], r[1]), packbf2(r[2], r[3]) };
            *(uint2*)(ws + KT_OFF + (size_t)(b * NN + n) * DD + d) = st;
        } else {
            const int c = mb - 64;
#pragma unroll
            for (int rr = 0; rr < 4; rr++) {
                const int cc = c + rr;
                const size_t off = V_OFF + (size_t)b * V2_B
                                 + (size_t)jt * 8192 + (size_t)(cc >> 4) * 512
                                 + (size_t)(lq * 16 + (cc & 15)) * 8 + sub * 4 + jj4;
                ws[off] = f2bf(acc[t][rr] + bv[cc]);
            }
        }
    }
}

// ---------------------------------------------------------------------------
// Kernel B: MFMA flash attention. Block = (b, i-group 16, c-half),
// grid (8,128) -> 1024 blocks, 4/CU (16 waves/CU). 4 waves = (jh) x (c-64).
// PV via v_mfma_f32_16x16x16_bf16: exp(S) C-layout IS the K=16 B-operand —
// zero shuffles. 2-deep prefetch. Symmetric epilogue: both j-halves exchange
// partials through LDS; each writes half the c-tiles (all waves active).
// XCD affinity: linear block id === b (mod 8). No-max softmax via exp2.
// ---------------------------------------------------------------------------
__global__ __launch_bounds__(256, 4) void attn_kernel(
    const float* __restrict__ x,
    const float* __restrict__ gamma,
    const unsigned short* __restrict__ ws,
    float* __restrict__ out)
{
    const int b    = blockIdx.x;        // 0..7  (XCD affinity)
    const int by   = blockIdx.y;        // 0..127
    const int ig   = by >> 1;           // i-group 0..63
    const int cs   = by & 1;            // c-half
    const int tid  = threadIdx.x;
    const int jh   = tid >> 7;          // j-half (waves 0,1 vs 2,3)
    const int cw   = (tid >> 6) & 1;    // c-64 within half
    const int lane = tid & 63;
    const int n    = lane & 15;         // col index: i (within tile)
    const int q4   = lane >> 4;
    const int i0   = ig * 16;
    const int cb   = cs * 128 + cw * 64;

    __shared__ float accL[2 * 2 * 8 * 64];  // 8 KB: [jh][cw][t*4+r (2 tiles)][lane]
    __shared__ float lL[2][16];

    const unsigned short* qT = ws + QT_OFF + (size_t)b * NN * DD;
    const unsigned short* kT = ws + KT_OFF + (size_t)b * NN * DD + (size_t)jh * 512 * DD;
    const unsigned short* vb = ws + V_OFF + (size_t)b * V2_B
                             + (size_t)jh * 16 * 8192 + (size_t)(cb >> 4) * 512
                             + (size_t)lane * 8;

    const bf16x8 qf = *(const bf16x8*)(qT + (size_t)(i0 + n) * DD + q4 * 8);

    f32x4 acc[4];
#pragma unroll
    for (int t = 0; t < 4; t++) acc[t] = (f32x4){0.f, 0.f, 0.f, 0.f};
    float lsum = 0.f;

    // 2-deep prefetch (last-iter over-reads land inside ws — harmless)
    bf16x8 kaS[2][2];
    bf16x8 vaS[2][4];
#pragma unroll
    for (int s = 0; s < 2; s++) {
        const int j0 = s * 32;
        kaS[s][0] = *(const bf16x8*)(kT + (size_t)(j0 + n) * DD + q4 * 8);
        kaS[s][1] = *(const bf16x8*)(kT + (size_t)(j0 + 16 + n) * DD + q4 * 8);
#pragma unroll
        for (int t = 0; t < 4; t++)
            vaS[s][t] = *(const bf16x8*)(vb + s * 8192 + t * 512);
    }

#pragma unroll 4
    for (int ch = 0; ch < 16; ch++) {
        const int st = ch & 1;
        const bf16x8 ka0c = kaS[st][0], ka1c = kaS[st][1];
        bf16x8 vac[4];
#pragma unroll
        for (int t = 0; t < 4; t++) vac[t] = vaS[st][t];

        {   // prefetch ch+2 into this stage
            const int j0 = (ch + 2) * 32;
            kaS[st][0] = *(const bf16x8*)(kT + (size_t)(j0 + n) * DD + q4 * 8);
            kaS[st][1] = *(const bf16x8*)(kT + (size_t)(j0 + 16 + n) * DD + q4 * 8);
#pragma unroll
            for (int t = 0; t < 4; t++)
                vaS[st][t] = *(const bf16x8*)(vb + (ch + 2) * 8192 + t * 512);
        }

        const f32x4 z = {0.f, 0.f, 0.f, 0.f};
        f32x4 s0 = __builtin_amdgcn_mfma_f32_16x16x32_bf16(ka0c, qf, z, 0, 0, 0);
        f32x4 s1 = __builtin_amdgcn_mfma_f32_16x16x32_bf16(ka1c, qf, z, 0, 0, 0);

        float p0[4], p1[4];
#pragma unroll
        for (int r = 0; r < 4; r++) {
            p0[r] = exp2f(s0[r]);
            p1[r] = exp2f(s1[r]);
            lsum += p0[r] + p1[r];
        }

        // P C-layout == K=16 B-operand layout: pack and go, no shuffles.
        union { unsigned int u[2]; bf16x4 v; } pk0, pk1;
        pk0.u[0] = packbf2(p0[0], p0[1]); pk0.u[1] = packbf2(p0[2], p0[3]);
        pk1.u[0] = packbf2(p1[0], p1[1]); pk1.u[1] = packbf2(p1[2], p1[3]);

#pragma unroll
        for (int t = 0; t < 4; t++) {
            union { bf16x8 w; bf16x4 h[2]; } vs; vs.w = vac[t];
            acc[t] = __builtin_amdgcn_mfma_f32_16x16x16bf16_1k(vs.h[0], pk0.v, acc[t], 0, 0, 0);
            acc[t] = __builtin_amdgcn_mfma_f32_16x16x16bf16_1k(vs.h[1], pk1.v, acc[t], 0, 0, 0);
        }
    }

    lsum += __shfl_xor(lsum, 16, 64);
    lsum += __shfl_xor(lsum, 32, 64);

    // symmetric exchange: each jh stores the 2 c-tiles the OTHER group writes
    // out. jh=0 keeps tiles {0,1}, exports {2,3}; jh=1 keeps {2,3}, exports {0,1}.
    const int keep = jh * 2;        // base tile index this group writes to out
    const int give = 2 - jh * 2;    // base tile index this group exports
#pragma unroll
    for (int t = 0; t < 2; t++)
#pragma unroll
        for (int r = 0; r < 4; r++)
            accL[(((jh * 2 + cw) * 8) + t * 4 + r) * 64 + lane] = acc[give + t][r];
    if (cw == 0 && lane < 16) lL[jh][lane] = lsum;
    __syncthreads();

    {
        const float rl = gamma[0] / (lsum + lL[1 - jh][n]);
#pragma unroll
        for (int t = 0; t < 2; t++) {
#pragma unroll
            for (int r = 0; r < 4; r++) {
                const int c = cb + (keep + t) * 16 + q4 * 4 + r;
                const size_t idx = (size_t)(b * CH + c) * NN + i0 + n;
                const float a = acc[keep + t][r]
                              + accL[((((1 - jh) * 2 + cw) * 8) + t * 4 + r) * 64 + lane];
                out[idx] = a * rl + x[idx];
            }
        }
    }
}

extern "C" void kernel_launch(void* const* d_in, const int* in_sizes, int n_in,
                              void* d_out, int out_size, void* d_ws, size_t ws_size,
                              hipStream_t stream) {
    (void)in_sizes; (void)n_in; (void)out_size; (void)ws_size;
    const float* x     = (const float*)d_in[0];
    const float* Wq    = (const float*)d_in[1];
    const float* bq    = (const float*)d_in[2];
    const float* Wk    = (const float*)d_in[3];
    const float* bk    = (const float*)d_in[4];
    const float* Wv    = (const float*)d_in[5];
    const float* bv    = (const float*)d_in[6];
    const float* Wr    = (const float*)d_in[7];
    // d_in[8] = br: j-constant logit shift -> softmax-invariant, dropped.
    const float* gamma = (const float*)d_in[9];
    float* out = (float*)d_out;
    unsigned short* ws = (unsigned short*)d_ws;

    wrepack_kernel<<<80, 256, 0, stream>>>(Wq, Wk, Wv, ws);
    proj_kernel<<<dim3(64, 8), 256, 0, stream>>>(x, bq, bk, bv, Wr, ws);
    attn_kernel<<<dim3(8, 128), 256, 0, stream>>>(x, gamma, ws, out);
}

// Round 11
// 107.914 us; speedup vs baseline: 1.0730x; 1.0730x over previous
//
#include <hip/hip_runtime.h>
#include <hip/hip_bf16.h>

#define BATCH 8
#define CH    256
#define NN    1024
#define DD    32

// ws layout (bf16 shorts):
//   qT [b][i][d]   (scale*log2e folded)      512 KB
//   kT [b][j][d]   (rp + bias folded)        512 KB
//   v2 [b][jt=32][ct=16][lane=64][jj=8]      4 MB   (MFMA A-frag-ready)
//   wf [mf=20][kc=8][lane=64][jj=8]          160 KB (W in A-frag-ready bf16)
#define QT_OFF 0
#define KT_OFF (BATCH * NN * DD)
#define V_OFF  (2 * BATCH * NN * DD)
#define V2_B   (NN * CH)                       // shorts per batch in v2
#define WF_OFF (V_OFF + BATCH * V2_B)          // 2621440

// 1/sqrt(32) * log2(e): softmax via exp2 (v_exp_f32 is native 2^x)
#define SCALE_Q (0.17677669529663687f * 1.4426950408889634f)
#define INV31 (1.0f / 31.0f)

typedef __attribute__((ext_vector_type(4))) float f32x4;
typedef __attribute__((ext_vector_type(8))) short bf16x8;

__device__ __forceinline__ unsigned int packbf2(float lo, float hi) {
    __hip_bfloat162 h = __float22bfloat162_rn(make_float2(lo, hi));
    union { __hip_bfloat162 h; unsigned int u; } cv; cv.h = h;
    return cv.u;
}
__device__ __forceinline__ unsigned short f2bf(float x) {
    union { float f; unsigned int u; } v; v.f = x;
    return (unsigned short)((v.u + 0x7FFFu + ((v.u >> 16) & 1u)) >> 16);
}

// ---------------------------------------------------------------------------
// Kernel W: repack W_all (320x256 fp32) into MFMA-A-fragment-ready bf16.
// ---------------------------------------------------------------------------
__global__ __launch_bounds__(256) void wrepack_kernel(
    const float* __restrict__ Wq, const float* __restrict__ Wk,
    const float* __restrict__ Wv, unsigned short* __restrict__ ws)
{
    const int gid = blockIdx.x * 256 + threadIdx.x;   // 0..20479
    const int e = gid * 4;
    const int m = e >> 8;
    const int k = e & 255;
    const float* src = (m < 32) ? (Wq + m * CH + k)
                     : (m < 64) ? (Wk + (m - 32) * CH + k)
                                : (Wv + (m - 64) * CH + k);
    const float4 w = *(const float4*)src;
    const int mf = m >> 4, kc = k >> 5;
    const int lf = ((k >> 3) & 3) * 16 + (m & 15);
    const int jj = k & 7;                              // 0 or 4
    uint2 st = { packbf2(w.x, w.y), packbf2(w.z, w.w) };
    *(uint2*)(ws + WF_OFF + ((size_t)(mf * 8 + kc) * 64 + lf) * 8 + jj) = st;
}

// ---------------------------------------------------------------------------
// Kernel P: MFMA projection, double-buffered across kc.
// ---------------------------------------------------------------------------
__global__ __launch_bounds__(256, 2) void proj_kernel(
    const float* __restrict__ x,
    const float* __restrict__ bq, const float* __restrict__ bk,
    const float* __restrict__ bv, const float* __restrict__ Wr,
    unsigned short* __restrict__ ws)
{
    const int nt   = blockIdx.x;   // 0..63
    const int b    = blockIdx.y;   // 0..7
    const int tid  = threadIdx.x;
    const int wv   = tid >> 6;     // 0..3 (m-group)
    const int lane = tid & 63;
    const int n16  = lane & 15;
    const int q4   = lane >> 4;
    const int n    = nt * 16 + n16;

    f32x4 acc[5];
#pragma unroll
    for (int t = 0; t < 5; t++) acc[t] = (f32x4){0.f, 0.f, 0.f, 0.f};

    const unsigned short* wfl = ws + WF_OFF + (size_t)lane * 8;
    const float* xb = x + (size_t)b * CH * NN + n;

    float  bx[2][8];
    bf16x8 af[2][5];
#pragma unroll
    for (int jj = 0; jj < 8; jj++)
        bx[0][jj] = xb[(size_t)(q4 * 8 + jj) * NN];
#pragma unroll
    for (int t = 0; t < 5; t++)
        af[0][t] = *(const bf16x8*)(wfl + (size_t)((wv * 5 + t) * 8) * 512);

#pragma unroll
    for (int kc = 0; kc < 8; kc++) {
        const int s = kc & 1;
        if (kc < 7) {
            const int kofs = (kc + 1) * 32 + q4 * 8;
#pragma unroll
            for (int jj = 0; jj < 8; jj++)
                bx[s ^ 1][jj] = xb[(size_t)(kofs + jj) * NN];
#pragma unroll
            for (int t = 0; t < 5; t++)
                af[s ^ 1][t] = *(const bf16x8*)(wfl + (size_t)((wv * 5 + t) * 8 + kc + 1) * 512);
        }
        union { unsigned int u[4]; bf16x8 v; } bf;
#pragma unroll
        for (int p = 0; p < 4; p++) bf.u[p] = packbf2(bx[s][2 * p], bx[s][2 * p + 1]);
#pragma unroll
        for (int t = 0; t < 5; t++)
            acc[t] = __builtin_amdgcn_mfma_f32_16x16x32_bf16(af[s][t], bf.v, acc[t], 0, 0, 0);
    }

    const int jt  = n >> 5;          // v2 indices for this thread's j (= n)
    const int q4p = (n >> 3) & 3;
    const int jj  = n & 7;
#pragma unroll
    for (int t = 0; t < 5; t++) {
        const int mf = wv * 5 + t;
        const int mb = mf * 16 + q4 * 4;
        if (mb < 32) {
            const float r0 = (acc[t][0] + bq[mb + 0]) * SCALE_Q;
            const float r1 = (acc[t][1] + bq[mb + 1]) * SCALE_Q;
            const float r2 = (acc[t][2] + bq[mb + 2]) * SCALE_Q;
            const float r3 = (acc[t][3] + bq[mb + 3]) * SCALE_Q;
            uint2 st = { packbf2(r0, r1), packbf2(r2, r3) };
            *(uint2*)(ws + QT_OFF + (size_t)(b * NN + n) * DD + mb) = st;
        } else if (mb < 64) {
            const int d = mb - 32;
            const float An = (float)(n >> 5) * INV31;
            const float Bn = (float)(n & 31) * INV31;
            float r[4];
#pragma unroll
            for (int rr = 0; rr < 4; rr++)
                r[rr] = acc[t][rr] + bk[d + rr] - An * Wr[2 * (d + rr)] - Bn * Wr[2 * (d + rr) + 1];
            uint2 st = { packbf2(r[0], r[1]), packbf2(r[2], r[3]) };
            *(uint2*)(ws + KT_OFF + (size_t)(b * NN + n) * DD + d) = st;
        } else {
            const int c = mb - 64;
#pragma unroll
            for (int rr = 0; rr < 4; rr++) {
                const int cc = c + rr;
                const size_t off = V_OFF + (size_t)b * V2_B
                                 + (size_t)jt * 8192 + (size_t)(cc >> 4) * 512
                                 + (size_t)(q4p * 16 + (cc & 15)) * 8 + jj;
                ws[off] = f2bf(acc[t][rr] + bv[cc]);
            }
        }
    }
}

// ---------------------------------------------------------------------------
// Kernel B: MFMA flash attention, occupancy-shaped: 1024 blocks x 256 thr,
// block = (b, i-group of 16, c-half); 4 waves = (j-half) x (c-sub-64).
// Grid (8,128): linear block id === b (mod 8) -> all blocks of a batch land
// on one XCD, keeping that batch's K/V L2-resident (XCD-affinity swizzle).
// No-max softmax via exp2, 1-deep prefetch, single barrier.
// (R7 configuration — session best, 108.2 us.)
// ---------------------------------------------------------------------------
__global__ __launch_bounds__(256, 4) void attn_kernel(
    const float* __restrict__ x,
    const float* __restrict__ gamma,
    const unsigned short* __restrict__ ws,
    float* __restrict__ out)
{
    const int b    = blockIdx.x;        // 0..7  (XCD affinity)
    const int by   = blockIdx.y;        // 0..127
    const int ig   = by >> 1;           // i-group 0..63
    const int cs   = by & 1;            // c-half
    const int tid  = threadIdx.x;
    const int jh   = tid >> 7;          // j-half (waves 0,1 vs 2,3)
    const int cw   = (tid >> 6) & 1;    // c-sub within half
    const int lane = tid & 63;
    const int n    = lane & 15;         // col index: i (within tile)
    const int q4   = lane >> 4;
    const int i0   = ig * 16;
    const int cb   = cs * 128 + cw * 64;

    __shared__ float accL[2 * 16 * 64];  // 8 KB: [cw][reg][lane]
    __shared__ float lL[16];

    const unsigned short* qT = ws + QT_OFF + (size_t)b * NN * DD;
    const unsigned short* kT = ws + KT_OFF + (size_t)b * NN * DD + (size_t)jh * 512 * DD;
    const unsigned short* vb = ws + V_OFF + (size_t)b * V2_B
                             + (size_t)jh * 16 * 8192 + (size_t)(cb >> 4) * 512
                             + (size_t)lane * 8;

    const bf16x8 qf = *(const bf16x8*)(qT + (size_t)(i0 + n) * DD + q4 * 8);

    f32x4 acc[4];
#pragma unroll
    for (int t = 0; t < 4; t++) acc[t] = (f32x4){0.f, 0.f, 0.f, 0.f};
    float lsum = 0.f;

    // 1-deep prefetch (over-reads past region end land inside ws — harmless)
    bf16x8 ka0 = *(const bf16x8*)(kT + (size_t)(n) * DD + q4 * 8);
    bf16x8 ka1 = *(const bf16x8*)(kT + (size_t)(16 + n) * DD + q4 * 8);
    bf16x8 va[4];
#pragma unroll
    for (int t = 0; t < 4; t++)
        va[t] = *(const bf16x8*)(vb + t * 512);

    const int qh2 = (q4 & 1) * 2;
    int src[4];
#pragma unroll
    for (int t = 0; t < 4; t++) src[t] = (qh2 + (t >> 1)) * 16 + n;

#pragma unroll 4
    for (int ch = 0; ch < 16; ch++) {
        const bf16x8 ka0c = ka0, ka1c = ka1;
        bf16x8 vac[4];
#pragma unroll
        for (int t = 0; t < 4; t++) vac[t] = va[t];

        {   // prefetch next chunk
            const int j0 = (ch + 1) * 32;
            ka0 = *(const bf16x8*)(kT + (size_t)(j0 + n) * DD + q4 * 8);
            ka1 = *(const bf16x8*)(kT + (size_t)(j0 + 16 + n) * DD + q4 * 8);
#pragma unroll
            for (int t = 0; t < 4; t++)
                va[t] = *(const bf16x8*)(vb + (ch + 1) * 8192 + t * 512);
        }

        const f32x4 z = {0.f, 0.f, 0.f, 0.f};
        f32x4 s0 = __builtin_amdgcn_mfma_f32_16x16x32_bf16(ka0c, qf, z, 0, 0, 0);
        f32x4 s1 = __builtin_amdgcn_mfma_f32_16x16x32_bf16(ka1c, qf, z, 0, 0, 0);

        float p0[4], p1[4];
#pragma unroll
        for (int r = 0; r < 4; r++) {
            p0[r] = exp2f(s0[r]);
            p1[r] = exp2f(s1[r]);
            lsum += p0[r] + p1[r];
        }

        unsigned int pk0[2] = { packbf2(p0[0], p0[1]), packbf2(p0[2], p0[3]) };
        unsigned int pk1[2] = { packbf2(p1[0], p1[1]), packbf2(p1[2], p1[3]) };
        union { unsigned int u[4]; bf16x8 v; } pf;
#pragma unroll
        for (int t = 0; t < 4; t++) {
            const unsigned int lo = (unsigned int)__shfl((int)pk0[t & 1], src[t], 64);
            const unsigned int hi = (unsigned int)__shfl((int)pk1[t & 1], src[t], 64);
            pf.u[t] = (q4 >= 2) ? hi : lo;
        }

#pragma unroll
        for (int t = 0; t < 4; t++)
            acc[t] = __builtin_amdgcn_mfma_f32_16x16x32_bf16(vac[t], pf.v, acc[t], 0, 0, 0);
    }

    lsum += __shfl_xor(lsum, 16, 64);
    lsum += __shfl_xor(lsum, 32, 64);

    if (jh == 1) {
#pragma unroll
        for (int t = 0; t < 4; t++)
#pragma unroll
            for (int r = 0; r < 4; r++)
                accL[(cw * 16 + t * 4 + r) * 64 + lane] = acc[t][r];
        if (cw == 0 && lane < 16) lL[lane] = lsum;
    }
    __syncthreads();

    if (jh == 0) {
        const float rl = gamma[0] / (lsum + lL[n]);
#pragma unroll
        for (int t = 0; t < 4; t++) {
#pragma unroll
            for (int r = 0; r < 4; r++) {
                const int c = cb + t * 16 + q4 * 4 + r;
                const size_t idx = (size_t)(b * CH + c) * NN + i0 + n;
                const float a = acc[t][r] + accL[(cw * 16 + t * 4 + r) * 64 + lane];
                out[idx] = a * rl + x[idx];
            }
        }
    }
}

extern "C" void kernel_launch(void* const* d_in, const int* in_sizes, int n_in,
                              void* d_out, int out_size, void* d_ws, size_t ws_size,
                              hipStream_t stream) {
    (void)in_sizes; (void)n_in; (void)out_size; (void)ws_size;
    const float* x     = (const float*)d_in[0];
    const float* Wq    = (const float*)d_in[1];
    const float* bq    = (const float*)d_in[2];
    const float* Wk    = (const float*)d_in[3];
    const float* bk    = (const float*)d_in[4];
    const float* Wv    = (const float*)d_in[5];
    const float* bv    = (const float*)d_in[6];
    const float* Wr    = (const float*)d_in[7];
    // d_in[8] = br: j-constant logit shift -> softmax-invariant, dropped.
    const float* gamma = (const float*)d_in[9];
    float* out = (float*)d_out;
    unsigned short* ws = (unsigned short*)d_ws;

    wrepack_kernel<<<80, 256, 0, stream>>>(Wq, Wk, Wv, ws);
    proj_kernel<<<dim3(64, 8), 256, 0, stream>>>(x, bq, bk, bv, Wr, ws);
    attn_kernel<<<dim3(8, 128), 256, 0, stream>>>(x, gamma, ws, out);
}